// Round 16
// baseline (314.343 us; speedup 1.0000x reference)
//
#include <hip/hip_runtime.h>
#include <math.h>

#define KCODES 1024
#define DDIM 256
#define NHW 4096              // H*W
#define NROWS 65536           // B*H*W
#define NELEM 16777216        // B*D*H*W
#define LOSS_OFF NELEM
#define INDS_OFF (NELEM + 1)

// ws layout (bytes)
#define WS_LOSS 0                          // double
#define WS_COUNT 8                         // int (+pad)
#define WS_LIST 16                         // int[65536]            -> 262160
#define WS_BV   262160                     // float[1024]           -> 266256
#define WS_BPP  266256                     // ushort[1024*512] 1MB  -> 1314832

// screen-gap threshold: worst-case |screen - emulated| <= ~6.3e-5 per value
// -> 1.26e-4 gap suffices; 2e-4 gives 1.6x margin. (validated rounds 4-15)
#define DELTA 2e-4f

using bf16x8 = __attribute__((ext_vector_type(8))) short;
using f32x16 = __attribute__((ext_vector_type(16))) float;

static __device__ __forceinline__ unsigned short f2bf(float f) {
  unsigned int u = __float_as_uint(f);
  u += 0x7fffu + ((u >> 16) & 1u);   // RNE
  return (unsigned short)(u >> 16);
}
static __device__ __forceinline__ float bf2f(unsigned short h) {
  return __uint_as_float(((unsigned int)h) << 16);
}

// ---- fused prep ----
// blocks 0..255: pre-fragment E for 32x32x16 B-operand, hi|lo split-bf16.
//   Bpp chunk (g32*32 + half*16 + ks), lane l holds code g32*32+(l&31),
//   d = ks*16 + (l>>5)*8 + j  (B layout: col=l&31, k=(l>>5)*8+j).
// blocks 256..259: numpy-pairwise ||e||^2 (validated round 2); block 259
//   thread 0 zeroes count/loss.
__global__ __launch_bounds__(256) void prep_kernel(const float* __restrict__ emb,
                                                   unsigned short* __restrict__ Bpp,
                                                   float* __restrict__ Bv,
                                                   int* __restrict__ count,
                                                   double* __restrict__ loss_acc) {
#pragma clang fp contract(off)
  if (blockIdx.x < 256) {
    const int i = blockIdx.x * 256 + threadIdx.x;   // 65536 threads
    const int l = i & 63;
    const int cb = (i >> 6) & 31;   // half*16 + ks
    const int g32 = i >> 11;        // 0..31
    const int code = g32 * 32 + (l & 31);
    const int half = cb >> 4;
    const int ks = cb & 15;
    const int d0 = ks * 16 + (l >> 5) * 8;
    const float* ep = emb + (size_t)code * DDIM + d0;
    unsigned short v[8];
#pragma unroll
    for (int j = 0; j < 8; ++j) {
      float x = ep[j];
      unsigned short h = f2bf(x);
      if (half == 0) v[j] = h;
      else v[j] = f2bf(x - bf2f(h));
    }
    unsigned short* dst = Bpp + ((size_t)(g32 * 32 + cb) * 64 + l) * 8;
#pragma unroll
    for (int j = 0; j < 8; ++j) dst[j] = v[j];
  } else {
    if (blockIdx.x == 259 && threadIdx.x == 0) {
      *count = 0;
      *loss_acc = 0.0;
    }
    const int k = (blockIdx.x - 256) * 256 + threadIdx.x;
    const float* p = emb + (size_t)k * DDIM;
    float half[2];
    for (int h = 0; h < 2; ++h) {
      float r[8];
#pragma unroll
      for (int j = 0; j < 8; ++j) {
        float v = p[h * 128 + j];
        r[j] = v * v;
      }
      for (int i = 8; i < 128; i += 8) {
#pragma unroll
        for (int j = 0; j < 8; ++j) {
          float v = p[h * 128 + i + j];
          r[j] += v * v;
        }
      }
      half[h] = ((r[0] + r[1]) + (r[2] + r[3])) + ((r[4] + r[5]) + (r[6] + r[7]));
    }
    Bv[k] = half[0] + half[1];
  }
}

// ---- MFMA split-bf16 screen, ROUND 16: 32x32x16 shape ----
// 64 rows x 1024 codes per block, 16 waves. Wave w owns ALL 64 rows x 64
// codes [w*64, w*64+64) as 2x2 tiles of 32x32 -> B chunks read ONCE per
// block (1 GB total L2 stream, was 2 GB), MFMA instr count halved.
// acc = 4 x f32x16 = 64 AGPR (unchanged box); per-kstep live frags:
// A 16 + B 8 regs (round-6-like shape -> no spill expected).
// A' LDS chunk ((half*16+ks)*2 + rt): lane l holds row rt*32+(l&31),
// d = ks*16 + (l>>5)*8 + j. Lane-contiguous b128 -> conflict-free.
__global__ __launch_bounds__(1024) void screen_kernel(
    const float* __restrict__ lat, const unsigned short* __restrict__ Bpp,
    const float* __restrict__ Bv, float* __restrict__ inds_f,
    int* __restrict__ list, int* __restrict__ count,
    double* __restrict__ loss_acc) {
  __shared__ __align__(16) char AsF[64 * 1024];   // 64 chunks x 1KB
  __shared__ float BvS[KCODES];
  __shared__ float Xsq[16][64];
  __shared__ float Mg1[64][17];
  __shared__ float Mg2[64][17];
  __shared__ int   Mgi[64][17];

  const int tid = threadIdx.x;
  const int n0 = blockIdx.x * 64;
  const int b = n0 >> 12;
  const int hw0 = n0 & 4095;

  BvS[tid] = Bv[tid];

  // ---- stage A' (fp32 -> hi/lo bf16) into 32x32x16 fragment layout ----
  {
    const int m = tid & 63;
    const int rt = m >> 5;
    const int m31 = m & 31;
    const int db0 = tid >> 6;   // 0..15; handles db0 and db0+16
    const float* base = lat + (size_t)b * (DDIM * NHW) + hw0 + m;
    float sq = 0.f;
#pragma unroll
    for (int t = 0; t < 2; ++t) {
      const int db = db0 + t * 16;   // 0..31 (8 d's each)
      const int d0 = db * 8;
      const int ks = db >> 1;        // kstep 0..15
      const int l5 = db & 1;         // k-half within kstep
      bf16x8 hv, lv;
#pragma unroll
      for (int j = 0; j < 8; ++j) {
        float x = __builtin_nontemporal_load(&base[(size_t)(d0 + j) * NHW]);
        sq += x * x;
        unsigned short h = f2bf(x);
        hv[j] = (short)h;
        lv[j] = (short)f2bf(x - bf2f(h));
      }
      const int slot = ((l5 << 5) | m31) * 16;
      *(bf16x8*)(AsF + (size_t)(ks * 2 + rt) * 1024 + slot) = hv;        // A_hi
      *(bf16x8*)(AsF + (size_t)(32 + ks * 2 + rt) * 1024 + slot) = lv;   // A_lo
    }
    Xsq[db0][m] = sq;
  }
  __syncthreads();

  const int w = tid >> 6;          // wave 0..15 -> codes [w*64, w*64+64)
  const int l = tid & 63;

  f32x16 acc[2][2];                // [rt: rows rt*32+..][ct: codes w*64+ct*32+..]
#pragma unroll
  for (int rt = 0; rt < 2; ++rt)
#pragma unroll
    for (int ct = 0; ct < 2; ++ct)
#pragma unroll
      for (int e = 0; e < 16; ++e) acc[rt][ct][e] = 0.f;

  const unsigned short* Bl = Bpp + (size_t)l * 8;
  const char* AsL = AsF + l * 16;  // lane-contiguous: zero bank conflicts

  for (int ks = 0; ks < 16; ++ks) {
    bf16x8 ahi[2], alo[2];
#pragma unroll
    for (int rt = 0; rt < 2; ++rt) {
      ahi[rt] = *(const bf16x8*)(AsL + (size_t)(ks * 2 + rt) * 1024);
      alo[rt] = *(const bf16x8*)(AsL + (size_t)(32 + ks * 2 + rt) * 1024);
    }
#pragma unroll
    for (int ct = 0; ct < 2; ++ct) {
      const int g32 = w * 2 + ct;
      bf16x8 bh = *(const bf16x8*)(Bl + (size_t)(g32 * 32 + ks) * 512);
      bf16x8 bl_ = *(const bf16x8*)(Bl + (size_t)(g32 * 32 + 16 + ks) * 512);
      acc[0][ct] = __builtin_amdgcn_mfma_f32_32x32x16_bf16(ahi[0], bh, acc[0][ct], 0, 0, 0);
      acc[1][ct] = __builtin_amdgcn_mfma_f32_32x32x16_bf16(ahi[1], bh, acc[1][ct], 0, 0, 0);
      acc[0][ct] = __builtin_amdgcn_mfma_f32_32x32x16_bf16(alo[0], bh, acc[0][ct], 0, 0, 0);
      acc[1][ct] = __builtin_amdgcn_mfma_f32_32x32x16_bf16(alo[1], bh, acc[1][ct], 0, 0, 0);
      acc[0][ct] = __builtin_amdgcn_mfma_f32_32x32x16_bf16(ahi[0], bl_, acc[0][ct], 0, 0, 0);
      acc[1][ct] = __builtin_amdgcn_mfma_f32_32x32x16_bf16(ahi[1], bl_, acc[1][ct], 0, 0, 0);
    }
  }

  // ---- epilogue: per-row top-2 in FLOAT ----
  // 32x32 C layout (HW-verified m74/m101): col = lane&31,
  // row = (reg&3) + 8*(reg>>2) + 4*(lane>>5). Each 32-lane half processes
  // a different row per reg; shfl width 32 keeps the reduce in-half.
#pragma unroll
  for (int rt = 0; rt < 2; ++rt) {
#pragma unroll
    for (int reg = 0; reg < 16; ++reg) {
      const int c0 = w * 64 + (l & 31);
      const float s0 = BvS[c0] - 2.0f * acc[rt][0][reg];
      const float s1 = BvS[c0 + 32] - 2.0f * acc[rt][1][reg];
      float m1, m2;
      int i1;
      if (s1 < s0) { m1 = s1; i1 = c0 + 32; m2 = s0; }   // strict: tie keeps c0
      else { m1 = s0; i1 = c0; m2 = s1; }
#pragma unroll
      for (int off = 1; off < 32; off <<= 1) {
        float o1 = __shfl_xor(m1, off, 32);
        float o2 = __shfl_xor(m2, off, 32);
        int oi = __shfl_xor(i1, off, 32);
        if (o1 < m1 || (o1 == m1 && oi < i1)) {
          m2 = fminf(m1, o2);
          m1 = o1; i1 = oi;
        } else {
          m2 = fminf(m2, o1);
        }
      }
      if ((l & 31) == 0) {
        const int row = rt * 32 + (reg & 3) + 8 * (reg >> 2) + 4 * (l >> 5);
        Mg1[row][w] = m1;
        Mg2[row][w] = m2;
        Mgi[row][w] = i1;
      }
    }
  }
  __syncthreads();

  if (tid < 64) {
    float g1 = 1e30f, g2 = 1e30f;
    int gi = 1 << 30;
#pragma unroll
    for (int sl = 0; sl < 16; ++sl) {
      const float m1 = Mg1[tid][sl], m2 = Mg2[tid][sl];
      const int ii = Mgi[tid][sl];
      if (m1 < g1 || (m1 == g1 && ii < gi)) {
        g2 = fminf(g1, m2);
        g1 = m1; gi = ii;
      } else {
        g2 = fminf(g2, m1);
      }
    }
    const int n = n0 + tid;
    inds_f[n] = (float)gi;
    if (g2 - g1 < DELTA) {
      int p = atomicAdd(count, 1);
      list[p] = n;
    }
    // loss: sum over rows of ||x||^2 + (||e_win||^2 - 2 x.e_win)
    float x2 = 0.f;
#pragma unroll
    for (int k = 0; k < 16; ++k) x2 += Xsq[k][tid];
    float rowloss = x2 + g1;
    for (int off = 32; off > 0; off >>= 1)
      rowloss += __shfl_down(rowloss, off, 64);
    if (tid == 0) atomicAdd(loss_acc, (double)rowloss);
  }
}

// ---- exact fp32-chain rescan of flagged rows (ROUND-12 validated form) ----
__global__ __launch_bounds__(256) void refine_kernel(
    const float* __restrict__ lat, const float* __restrict__ emb,
    const float* __restrict__ Bv, float* __restrict__ inds_f,
    const int* __restrict__ list, const int* __restrict__ count) {
#pragma clang fp contract(off)
  __shared__ float xs[8][DDIM];
  __shared__ float rjs[8][2][8];
  __shared__ float Asm[8];
  __shared__ float rsv[4][8];
  __shared__ int rsi[4][8];
  const int cnt = *count;
  const int tid = threadIdx.x;
  for (int base = blockIdx.x * 8; base < cnt; base += gridDim.x * 8) {
    const int nr = min(8, cnt - base);
    for (int r = 0; r < nr; ++r) {
      const int n = list[base + r];
      const int bb = n >> 12, hw = n & 4095;
      xs[r][tid] = lat[((size_t)(bb * DDIM + tid)) * NHW + hw];
    }
    __syncthreads();

    // numpy pairwise ||x||^2 (== validated a_kernel chain)
    if (tid < 128) {
      const int r = tid >> 4, h = (tid >> 3) & 1, j = tid & 7;
      const float* xr = &xs[r][h * 128 + j];
      float v = xr[0];
      float acc = v * v;
      for (int s = 1; s < 16; ++s) { v = xr[s * 8]; acc += v * v; }
      rjs[r][h][j] = acc;
    }
    __syncthreads();
    if (tid < 8) {
      const float* q0 = rjs[tid][0];
      const float* q1 = rjs[tid][1];
      float h0 = ((q0[0] + q0[1]) + (q0[2] + q0[3])) + ((q0[4] + q0[5]) + (q0[6] + q0[7]));
      float h1 = ((q1[0] + q1[1]) + (q1[2] + q1[3])) + ((q1[4] + q1[5]) + (q1[6] + q1[7]));
      Asm[tid] = h0 + h1;
    }
    __syncthreads();

    float best[8];
    int bidx[8];
#pragma unroll
    for (int r = 0; r < 8; ++r) { best[r] = 1e30f; bidx[r] = KCODES; }

    for (int c = 0; c < 4; ++c) {
      const int k = c * 256 + tid;
      const float4* e4 = (const float4*)(emb + (size_t)k * DDIM);
      float acc[8] = {0.f, 0.f, 0.f, 0.f, 0.f, 0.f, 0.f, 0.f};
      for (int d4 = 0; d4 < 64; ++d4) {
        const float4 e = e4[d4];
#pragma unroll
        for (int r = 0; r < 8; ++r) {
          acc[r] = __builtin_fmaf(xs[r][d4 * 4 + 0], e.x, acc[r]);
          acc[r] = __builtin_fmaf(xs[r][d4 * 4 + 1], e.y, acc[r]);
          acc[r] = __builtin_fmaf(xs[r][d4 * 4 + 2], e.z, acc[r]);
          acc[r] = __builtin_fmaf(xs[r][d4 * 4 + 3], e.w, acc[r]);
        }
      }
      const float bk = Bv[k];
#pragma unroll
      for (int r = 0; r < 8; ++r) {
        const float S = Asm[r] + bk;        // fl(A+B)
        const float s = S - 2.0f * acc[r];  // fl(S - 2M)
        if (s < best[r] || (s == best[r] && k < bidx[r])) { best[r] = s; bidx[r] = k; }
      }
    }

    // cross-lane lexicographic (val, idx) min per row
#pragma unroll
    for (int r = 0; r < 8; ++r) {
      float bv = best[r];
      int bi = bidx[r];
      for (int off = 32; off > 0; off >>= 1) {
        const float ov = __shfl_down(bv, off, 64);
        const int oi = __shfl_down(bi, off, 64);
        if (ov < bv || (ov == bv && oi < bi)) { bv = ov; bi = oi; }
      }
      const int lane = tid & 63, wid = tid >> 6;
      if (lane == 0) { rsv[wid][r] = bv; rsi[wid][r] = bi; }
    }
    __syncthreads();
    if (tid < 8 && tid < nr) {
      float bv = rsv[0][tid];
      int bi = rsi[0][tid];
      for (int ww = 1; ww < 4; ++ww) {
        const float ov = rsv[ww][tid];
        const int oi = rsi[ww][tid];
        if (ov < bv || (ov == bv && oi < bi)) { bv = ov; bi = oi; }
      }
      inds_f[list[base + tid]] = (float)bi;
    }
    __syncthreads();
  }
}

// ---- qwrite v2: out = quant = emb[ind], LDS-staged transposed gather ----
// (VALIDATED rounds 12/15; finalize fused; nontemporal out stores)
__global__ __launch_bounds__(256) void qwrite_kernel(
    const float* __restrict__ emb, const float* __restrict__ inds_f,
    const double* __restrict__ loss_acc, float* __restrict__ out) {
  __shared__ float Ls[256][65];
  const int tid = threadIdx.x;
  const int n0 = blockIdx.x * 64;
  const int b = n0 >> 12;
  const int hw0 = n0 & 4095;

  if (blockIdx.x == 0 && tid == 0) {
    double mse = *loss_acc / (double)NELEM;
    out[LOSS_OFF] = (float)(1.25 * mse);  // BETA*mse + ALPHA*mse
  }

  // stage: thread t handles row m = t>>2, quarter q = t&3 (64 floats)
  {
    const int m = tid >> 2;
    const int q = tid & 3;
    const int ind = (int)inds_f[n0 + m];
    const float4* src = (const float4*)(emb + (size_t)ind * DDIM + q * 64);
#pragma unroll
    for (int jj = 0; jj < 16; ++jj) {
      const int j4 = (jj + q * 4) & 15;   // rotate per-q: write conflicts 4->2-way
      float4 v = src[j4];
      const int e = q * 64 + j4 * 4;
      Ls[e + 0][m] = v.x;
      Ls[e + 1][m] = v.y;
      Ls[e + 2][m] = v.z;
      Ls[e + 3][m] = v.w;
    }
  }
  __syncthreads();

  // write: lane m = tid&63 covers hw0+m; wave (tid>>6) strides d
  {
    const int m = tid & 63;
    const int wv = tid >> 6;   // 0..3
    float* obase = out + (size_t)b * (DDIM * NHW) + hw0 + m;
#pragma unroll
    for (int i = 0; i < 64; ++i) {
      const int d = i * 4 + wv;
      __builtin_nontemporal_store(Ls[d][m], &obase[(size_t)d * NHW]);
    }
  }
}

extern "C" void kernel_launch(void* const* d_in, const int* in_sizes, int n_in,
                              void* d_out, int out_size, void* d_ws, size_t ws_size,
                              hipStream_t stream) {
  const float* lat = (const float*)d_in[0];
  const float* emb = (const float*)d_in[1];
  float* out = (float*)d_out;
  char* ws = (char*)d_ws;
  double* loss_acc = (double*)(ws + WS_LOSS);
  int* count = (int*)(ws + WS_COUNT);
  int* list = (int*)(ws + WS_LIST);
  float* Bv = (float*)(ws + WS_BV);
  unsigned short* Bpp = (unsigned short*)(ws + WS_BPP);
  float* inds_f = out + INDS_OFF;

  hipLaunchKernelGGL(prep_kernel, dim3(260), dim3(256), 0, stream,
                     emb, Bpp, Bv, count, loss_acc);
  hipLaunchKernelGGL(screen_kernel, dim3(NROWS / 64), dim3(1024), 0, stream,
                     lat, Bpp, Bv, inds_f, list, count, loss_acc);
  hipLaunchKernelGGL(refine_kernel, dim3(4096), dim3(256), 0, stream,
                     lat, emb, Bv, inds_f, list, count);
  hipLaunchKernelGGL(qwrite_kernel, dim3(NROWS / 64), dim3(256), 0, stream,
                     emb, inds_f, loss_acc, out);
}

// Round 17
// 244.697 us; speedup vs baseline: 1.2846x; 1.2846x over previous
//
#include <hip/hip_runtime.h>
#include <math.h>

#define KCODES 1024
#define DDIM 256
#define NHW 4096              // H*W
#define NROWS 65536           // B*H*W
#define NELEM 16777216        // B*D*H*W
#define LOSS_OFF NELEM
#define INDS_OFF (NELEM + 1)

// ws layout (bytes)
#define WS_LOSS 0                          // double
#define WS_COUNT 8                         // int (+pad)
#define WS_LIST 16                         // int[65536]            -> 262160
#define WS_BV   262160                     // float[1024]           -> 266256
#define WS_BPP  266256                     // ushort[1024*512] 1MB  -> 1314832

// screen-gap threshold: worst-case |screen - emulated| <= ~6.3e-5 per value
// -> 1.26e-4 gap suffices; 2e-4 gives 1.6x margin. (validated rounds 4-16)
#define DELTA 2e-4f

using bf16x8 = __attribute__((ext_vector_type(8))) short;
using f32x4  = __attribute__((ext_vector_type(4))) float;

static __device__ __forceinline__ unsigned short f2bf(float f) {
  unsigned int u = __float_as_uint(f);
  u += 0x7fffu + ((u >> 16) & 1u);   // RNE
  return (unsigned short)(u >> 16);
}
static __device__ __forceinline__ float bf2f(unsigned short h) {
  return __uint_as_float(((unsigned int)h) << 16);
}

// ---- fused prep: blocks 0..255 pre-fragment E (hi|lo split-bf16, validated);
//      blocks 256..259 compute numpy-pairwise ||e||^2 (validated round 2);
//      block 259 also zeroes count/loss (memset launch folded, r15) ----
__global__ __launch_bounds__(256) void prep_kernel(const float* __restrict__ emb,
                                                   unsigned short* __restrict__ Bpp,
                                                   float* __restrict__ Bv,
                                                   int* __restrict__ count,
                                                   double* __restrict__ loss_acc) {
#pragma clang fp contract(off)
  if (blockIdx.x < 256) {
    const int i = blockIdx.x * 256 + threadIdx.x;   // 65536 threads
    const int l = i & 63;
    const int kb = (i >> 6) & 15;
    const int g = i >> 10;
    const int code = g * 16 + (l & 15);
    const int kp0 = kb * 32 + (l >> 4) * 8;         // whole 8-chunk same half
    const int hi_half = (kp0 < 256);
    const int d0 = hi_half ? kp0 : (kp0 - 256);
    const float* ep = emb + (size_t)code * DDIM + d0;
    unsigned short v[8];
#pragma unroll
    for (int j = 0; j < 8; ++j) {
      float x = ep[j];
      unsigned short h = f2bf(x);
      if (hi_half) v[j] = h;
      else v[j] = f2bf(x - bf2f(h));
    }
    unsigned short* dst = Bpp + ((size_t)(g * 16 + kb) * 64 + l) * 8;
#pragma unroll
    for (int j = 0; j < 8; ++j) dst[j] = v[j];
  } else {
    if (blockIdx.x == 259 && threadIdx.x == 0) {
      *count = 0;
      *loss_acc = 0.0;
    }
    const int k = (blockIdx.x - 256) * 256 + threadIdx.x;
    const float* p = emb + (size_t)k * DDIM;
    float half[2];
    for (int h = 0; h < 2; ++h) {
      float r[8];
#pragma unroll
      for (int j = 0; j < 8; ++j) {
        float v = p[h * 128 + j];
        r[j] = v * v;
      }
      for (int i = 8; i < 128; i += 8) {
#pragma unroll
        for (int j = 0; j < 8; ++j) {
          float v = p[h * 128 + i + j];
          r[j] += v * v;
        }
      }
      half[h] = ((r[0] + r[1]) + (r[2] + r[3])) + ((r[4] + r[5]) + (r[6] + r[7]));
    }
    Bv[k] = half[0] + half[1];
  }
}

// ---- MFMA split-bf16 screen: 64 rows x 1024 codes per block, 16 waves ----
// Round-6 validated body (fragment-order A' in LDS, conflict-free) +
// round-10/11 loss fusion + round-15 nontemporal lat loads.
// NO s_setprio (spill, r10). 16x16x32 shape (32x32 regressed, r16: same
// MFMA-pipe time, 5x epilogue VALU).
__global__ __launch_bounds__(1024) void screen_kernel(
    const float* __restrict__ lat, const unsigned short* __restrict__ Bpp,
    const float* __restrict__ Bv, float* __restrict__ inds_f,
    int* __restrict__ list, int* __restrict__ count,
    double* __restrict__ loss_acc) {
  __shared__ __align__(16) char AsF[64 * 1024];   // 64 chunks x 1KB
  __shared__ float BvS[KCODES];
  __shared__ float Xsq[16][64];
  __shared__ float Mg1[64][9];
  __shared__ float Mg2[64][9];
  __shared__ int   Mgi[64][9];

  const int tid = threadIdx.x;
  const int n0 = blockIdx.x * 64;
  const int b = n0 >> 12;
  const int hw0 = n0 & 4095;

  BvS[tid] = Bv[tid];

  // ---- stage A' (fp32 -> hi/lo bf16) directly into fragment layout ----
  {
    const int m = tid & 63;
    const int mr = m >> 4, lr15 = m & 15;
    const int db0 = tid >> 6;   // 0..15; handles db0 and db0+16
    const float* base = lat + (size_t)b * (DDIM * NHW) + hw0 + m;
    float sq = 0.f;
#pragma unroll
    for (int t = 0; t < 2; ++t) {
      const int db = db0 + t * 16;   // 0..31 (8 d's each)
      const int d0 = db * 8;
      const int tch = db >> 2;       // k-chunk 0..7
      const int q = db & 3;          // l>>4 slot
      bf16x8 hv, lv;
#pragma unroll
      for (int j = 0; j < 8; ++j) {
        float x = __builtin_nontemporal_load(&base[(size_t)(d0 + j) * NHW]);
        sq += x * x;
        unsigned short h = f2bf(x);
        hv[j] = (short)h;
        lv[j] = (short)f2bf(x - bf2f(h));
      }
      const int slot = (q * 16 + lr15) * 16;
      *(bf16x8*)(AsF + (size_t)(tch * 4 + mr) * 1024 + slot) = hv;
      *(bf16x8*)(AsF + (size_t)((8 + tch) * 4 + mr) * 1024 + slot) = lv;
    }
    Xsq[db0][m] = sq;
  }
  __syncthreads();

  const int w = tid >> 6;          // wave 0..15
  const int l = tid & 63;
  const int mhalf = w & 1;         // rows mhalf*32 + ...
  const int nslice = w >> 1;       // codes nslice*128 + ...
  const int lr = l & 15;
  const int lk = l >> 4;           // 0..3

  f32x4 acc[2][8];
#pragma unroll
  for (int mr = 0; mr < 2; ++mr)
#pragma unroll
    for (int nr = 0; nr < 8; ++nr)
      acc[mr][nr] = (f32x4){0.f, 0.f, 0.f, 0.f};

  const unsigned short* Bl = Bpp + (size_t)l * 8;
  const char* AsL = AsF + l * 16;  // lane-contiguous: zero bank conflicts

  for (int t = 0; t < 8; ++t) {
    bf16x8 afh[2], afl[2];
#pragma unroll
    for (int mr = 0; mr < 2; ++mr) {
      const int gmr = mhalf * 2 + mr;
      afh[mr] = *(const bf16x8*)(AsL + (size_t)(t * 4 + gmr) * 1024);
      afl[mr] = *(const bf16x8*)(AsL + (size_t)((8 + t) * 4 + gmr) * 1024);
    }
#pragma unroll
    for (int nr = 0; nr < 8; ++nr) {
      const int g = nslice * 8 + nr;
      bf16x8 bh = *(const bf16x8*)(Bl + (size_t)(g * 16 + t) * 512);
      bf16x8 bl = *(const bf16x8*)(Bl + (size_t)(g * 16 + 8 + t) * 512);
      acc[0][nr] = __builtin_amdgcn_mfma_f32_16x16x32_bf16(afh[0], bh, acc[0][nr], 0, 0, 0);
      acc[1][nr] = __builtin_amdgcn_mfma_f32_16x16x32_bf16(afh[1], bh, acc[1][nr], 0, 0, 0);
      acc[0][nr] = __builtin_amdgcn_mfma_f32_16x16x32_bf16(afl[0], bh, acc[0][nr], 0, 0, 0);
      acc[1][nr] = __builtin_amdgcn_mfma_f32_16x16x32_bf16(afl[1], bh, acc[1][nr], 0, 0, 0);
      acc[0][nr] = __builtin_amdgcn_mfma_f32_16x16x32_bf16(afh[0], bl, acc[0][nr], 0, 0, 0);
      acc[1][nr] = __builtin_amdgcn_mfma_f32_16x16x32_bf16(afh[1], bl, acc[1][nr], 0, 0, 0);
    }
  }

  // ---- epilogue: per-row top-2 in FLOAT (validated rounds 5-15) ----
  // C layout: col = lane&15 (code), row = (lane>>4)*4 + j
#pragma unroll
  for (int mr = 0; mr < 2; ++mr) {
#pragma unroll
    for (int j = 0; j < 4; ++j) {
      float m1 = 1e30f, m2 = 1e30f;
      int i1 = 1 << 30;
#pragma unroll
      for (int nr = 0; nr < 8; ++nr) {
        const int c = nslice * 128 + nr * 16 + lr;
        const float s = BvS[c] - 2.0f * acc[mr][nr][j];
        if (s < m1) { m2 = m1; m1 = s; i1 = c; }   // ascending c: strict keeps lowest
        else if (s < m2) m2 = s;
      }
#pragma unroll
      for (int off = 1; off < 16; off <<= 1) {
        float o1 = __shfl_xor(m1, off, 16);
        float o2 = __shfl_xor(m2, off, 16);
        int oi = __shfl_xor(i1, off, 16);
        if (o1 < m1 || (o1 == m1 && oi < i1)) {
          m2 = fminf(m1, o2);
          m1 = o1; i1 = oi;
        } else {
          m2 = fminf(m2, o1);
        }
      }
      if (lr == 0) {
        const int row = mhalf * 32 + mr * 16 + lk * 4 + j;
        Mg1[row][nslice] = m1;
        Mg2[row][nslice] = m2;
        Mgi[row][nslice] = i1;
      }
    }
  }
  __syncthreads();

  if (tid < 64) {
    float g1 = 1e30f, g2 = 1e30f;
    int gi = 1 << 30;
#pragma unroll
    for (int sl = 0; sl < 8; ++sl) {
      const float m1 = Mg1[tid][sl], m2 = Mg2[tid][sl];
      const int ii = Mgi[tid][sl];
      if (m1 < g1 || (m1 == g1 && ii < gi)) {
        g2 = fminf(g1, m2);
        g1 = m1; gi = ii;
      } else {
        g2 = fminf(g2, m1);
      }
    }
    const int n = n0 + tid;
    inds_f[n] = (float)gi;
    if (g2 - g1 < DELTA) {
      int p = atomicAdd(count, 1);
      list[p] = n;
    }
    // loss: sum over rows of ||x||^2 + (||e_win||^2 - 2 x.e_win)
    float x2 = 0.f;
#pragma unroll
    for (int k = 0; k < 16; ++k) x2 += Xsq[k][tid];
    float rowloss = x2 + g1;
    for (int off = 32; off > 0; off >>= 1)
      rowloss += __shfl_down(rowloss, off, 64);
    if (tid == 0) atomicAdd(loss_acc, (double)rowloss);
  }
}

// ---- exact fp32-chain rescan of flagged rows (ROUND-12 validated form) ----
__global__ __launch_bounds__(256) void refine_kernel(
    const float* __restrict__ lat, const float* __restrict__ emb,
    const float* __restrict__ Bv, float* __restrict__ inds_f,
    const int* __restrict__ list, const int* __restrict__ count) {
#pragma clang fp contract(off)
  __shared__ float xs[8][DDIM];
  __shared__ float rjs[8][2][8];
  __shared__ float Asm[8];
  __shared__ float rsv[4][8];
  __shared__ int rsi[4][8];
  const int cnt = *count;
  const int tid = threadIdx.x;
  for (int base = blockIdx.x * 8; base < cnt; base += gridDim.x * 8) {
    const int nr = min(8, cnt - base);
    for (int r = 0; r < nr; ++r) {
      const int n = list[base + r];
      const int bb = n >> 12, hw = n & 4095;
      xs[r][tid] = lat[((size_t)(bb * DDIM + tid)) * NHW + hw];
    }
    __syncthreads();

    // numpy pairwise ||x||^2 (== validated a_kernel chain)
    if (tid < 128) {
      const int r = tid >> 4, h = (tid >> 3) & 1, j = tid & 7;
      const float* xr = &xs[r][h * 128 + j];
      float v = xr[0];
      float acc = v * v;
      for (int s = 1; s < 16; ++s) { v = xr[s * 8]; acc += v * v; }
      rjs[r][h][j] = acc;
    }
    __syncthreads();
    if (tid < 8) {
      const float* q0 = rjs[tid][0];
      const float* q1 = rjs[tid][1];
      float h0 = ((q0[0] + q0[1]) + (q0[2] + q0[3])) + ((q0[4] + q0[5]) + (q0[6] + q0[7]));
      float h1 = ((q1[0] + q1[1]) + (q1[2] + q1[3])) + ((q1[4] + q1[5]) + (q1[6] + q1[7]));
      Asm[tid] = h0 + h1;
    }
    __syncthreads();

    float best[8];
    int bidx[8];
#pragma unroll
    for (int r = 0; r < 8; ++r) { best[r] = 1e30f; bidx[r] = KCODES; }

    for (int c = 0; c < 4; ++c) {
      const int k = c * 256 + tid;
      const float4* e4 = (const float4*)(emb + (size_t)k * DDIM);
      float acc[8] = {0.f, 0.f, 0.f, 0.f, 0.f, 0.f, 0.f, 0.f};
      for (int d4 = 0; d4 < 64; ++d4) {
        const float4 e = e4[d4];
#pragma unroll
        for (int r = 0; r < 8; ++r) {
          acc[r] = __builtin_fmaf(xs[r][d4 * 4 + 0], e.x, acc[r]);
          acc[r] = __builtin_fmaf(xs[r][d4 * 4 + 1], e.y, acc[r]);
          acc[r] = __builtin_fmaf(xs[r][d4 * 4 + 2], e.z, acc[r]);
          acc[r] = __builtin_fmaf(xs[r][d4 * 4 + 3], e.w, acc[r]);
        }
      }
      const float bk = Bv[k];
#pragma unroll
      for (int r = 0; r < 8; ++r) {
        const float S = Asm[r] + bk;        // fl(A+B)
        const float s = S - 2.0f * acc[r];  // fl(S - 2M)
        if (s < best[r] || (s == best[r] && k < bidx[r])) { best[r] = s; bidx[r] = k; }
      }
    }

    // cross-lane lexicographic (val, idx) min per row
#pragma unroll
    for (int r = 0; r < 8; ++r) {
      float bv = best[r];
      int bi = bidx[r];
      for (int off = 32; off > 0; off >>= 1) {
        const float ov = __shfl_down(bv, off, 64);
        const int oi = __shfl_down(bi, off, 64);
        if (ov < bv || (ov == bv && oi < bi)) { bv = ov; bi = oi; }
      }
      const int lane = tid & 63, wid = tid >> 6;
      if (lane == 0) { rsv[wid][r] = bv; rsi[wid][r] = bi; }
    }
    __syncthreads();
    if (tid < 8 && tid < nr) {
      float bv = rsv[0][tid];
      int bi = rsi[0][tid];
      for (int ww = 1; ww < 4; ++ww) {
        const float ov = rsv[ww][tid];
        const int oi = rsi[ww][tid];
        if (ov < bv || (ov == bv && oi < bi)) { bv = ov; bi = oi; }
      }
      inds_f[list[base + tid]] = (float)bi;
    }
    __syncthreads();
  }
}

// ---- qwrite v2: out = quant = emb[ind], LDS-staged transposed gather ----
// (VALIDATED rounds 12/15; finalize fused; nontemporal out stores)
__global__ __launch_bounds__(256) void qwrite_kernel(
    const float* __restrict__ emb, const float* __restrict__ inds_f,
    const double* __restrict__ loss_acc, float* __restrict__ out) {
  __shared__ float Ls[256][65];
  const int tid = threadIdx.x;
  const int n0 = blockIdx.x * 64;
  const int b = n0 >> 12;
  const int hw0 = n0 & 4095;

  if (blockIdx.x == 0 && tid == 0) {
    double mse = *loss_acc / (double)NELEM;
    out[LOSS_OFF] = (float)(1.25 * mse);  // BETA*mse + ALPHA*mse
  }

  // stage: thread t handles row m = t>>2, quarter q = t&3 (64 floats)
  {
    const int m = tid >> 2;
    const int q = tid & 3;
    const int ind = (int)inds_f[n0 + m];
    const float4* src = (const float4*)(emb + (size_t)ind * DDIM + q * 64);
#pragma unroll
    for (int jj = 0; jj < 16; ++jj) {
      const int j4 = (jj + q * 4) & 15;   // rotate per-q: write conflicts 4->2-way
      float4 v = src[j4];
      const int e = q * 64 + j4 * 4;
      Ls[e + 0][m] = v.x;
      Ls[e + 1][m] = v.y;
      Ls[e + 2][m] = v.z;
      Ls[e + 3][m] = v.w;
    }
  }
  __syncthreads();

  // write: lane m = tid&63 covers hw0+m; wave (tid>>6) strides d
  {
    const int m = tid & 63;
    const int wv = tid >> 6;   // 0..3
    float* obase = out + (size_t)b * (DDIM * NHW) + hw0 + m;
#pragma unroll
    for (int i = 0; i < 64; ++i) {
      const int d = i * 4 + wv;
      __builtin_nontemporal_store(Ls[d][m], &obase[(size_t)d * NHW]);
    }
  }
}

extern "C" void kernel_launch(void* const* d_in, const int* in_sizes, int n_in,
                              void* d_out, int out_size, void* d_ws, size_t ws_size,
                              hipStream_t stream) {
  const float* lat = (const float*)d_in[0];
  const float* emb = (const float*)d_in[1];
  float* out = (float*)d_out;
  char* ws = (char*)d_ws;
  double* loss_acc = (double*)(ws + WS_LOSS);
  int* count = (int*)(ws + WS_COUNT);
  int* list = (int*)(ws + WS_LIST);
  float* Bv = (float*)(ws + WS_BV);
  unsigned short* Bpp = (unsigned short*)(ws + WS_BPP);
  float* inds_f = out + INDS_OFF;

  hipLaunchKernelGGL(prep_kernel, dim3(260), dim3(256), 0, stream,
                     emb, Bpp, Bv, count, loss_acc);
  hipLaunchKernelGGL(screen_kernel, dim3(NROWS / 64), dim3(1024), 0, stream,
                     lat, Bpp, Bv, inds_f, list, count, loss_acc);
  hipLaunchKernelGGL(refine_kernel, dim3(4096), dim3(256), 0, stream,
                     lat, emb, Bv, inds_f, list, count);
  hipLaunchKernelGGL(qwrite_kernel, dim3(NROWS / 64), dim3(256), 0, stream,
                     emb, inds_f, loss_acc, out);
}